// Round 3
// baseline (315.787 us; speedup 1.0000x reference)
//
#include <hip/hip_runtime.h>

#define DDIM 256
#define HDIM 512

// ---------------------------------------------------------------------------
// offsets[t] = lower_bound(batch, t) for t in [0, G]; batch is sorted.
// Massively parallel so the 20 HBM-latency probes overlap across 4k threads.
// ---------------------------------------------------------------------------
__global__ __launch_bounds__(256) void offsets_kernel(
    const int* __restrict__ batch, int* __restrict__ offsets, int N, int G) {
  const int t = blockIdx.x * 256 + threadIdx.x;
  if (t > G) return;
  int lo = 0, hi = N;
  while (lo < hi) {
    const int mid = (lo + hi) >> 1;
    if (batch[mid] < t) lo = mid + 1;
    else hi = mid;
  }
  offsets[t] = lo;
}

// ---------------------------------------------------------------------------
// Wfused[i,:] = W_in[i,:] @ W1  (blocks 0..511, two 256-col halves per row)
// bvec[:]     = b_in    @ W1    (blocks 512..513)
// One output per thread; source row staged in LDS, W1 reads coalesced (L2).
// ---------------------------------------------------------------------------
__global__ __launch_bounds__(256) void wfused_kernel(
    const float* __restrict__ W_in, const float* __restrict__ b_in,
    const float* __restrict__ W1, float* __restrict__ Wfused,
    float* __restrict__ bvec) {
  __shared__ float vrow[DDIM];
  const int b = blockIdx.x;
  const bool is_b = (b >= 2 * DDIM);
  const int i = is_b ? 0 : (b >> 1);
  const int half = is_b ? (b - 2 * DDIM) : (b & 1);
  const float* src = is_b ? b_in : (W_in + (size_t)i * DDIM);
  vrow[threadIdx.x] = src[threadIdx.x];
  __syncthreads();

  const int j = half * 256 + threadIdx.x;
  float h = 0.f;
#pragma unroll 8
  for (int k = 0; k < DDIM; ++k) h += vrow[k] * W1[(size_t)k * HDIM + j];
  if (is_b) bvec[j] = h;
  else Wfused[(size_t)i * HDIM + j] = h;
}

// ---------------------------------------------------------------------------
// One block per segment: stream rows [offsets[g], offsets[g+1]) of x,
// register-accumulate float4 column slices (4 waves), LDS-reduce to srow,
// then matvec H[g,:] = relu(srow @ Wfused + cnt*bvec + b1) in the same block.
// ---------------------------------------------------------------------------
__global__ __launch_bounds__(256) void segsum_mlp_kernel(
    const float* __restrict__ x, const int* __restrict__ offsets,
    const float* __restrict__ Wfused, const float* __restrict__ bvec,
    const float* __restrict__ b1, float* __restrict__ H) {
  const int g = blockIdx.x;
  const int start = offsets[g], end = offsets[g + 1];
  __shared__ float red[3][DDIM];
  __shared__ float srow[DDIM];

  const int w  = threadIdx.x >> 6;          // wave 0..3
  const int c4 = (threadIdx.x & 63) << 2;   // column base

  float4 a0 = make_float4(0.f, 0.f, 0.f, 0.f);
  float4 a1 = make_float4(0.f, 0.f, 0.f, 0.f);
  int i = start + w;
  for (; i + 4 < end; i += 8) {
    const float4 v0 = *reinterpret_cast<const float4*>(x + (size_t)i * DDIM + c4);
    const float4 v1 = *reinterpret_cast<const float4*>(x + (size_t)(i + 4) * DDIM + c4);
    a0.x += v0.x; a0.y += v0.y; a0.z += v0.z; a0.w += v0.w;
    a1.x += v1.x; a1.y += v1.y; a1.z += v1.z; a1.w += v1.w;
  }
  if (i < end) {
    const float4 v0 = *reinterpret_cast<const float4*>(x + (size_t)i * DDIM + c4);
    a0.x += v0.x; a0.y += v0.y; a0.z += v0.z; a0.w += v0.w;
  }
  a0.x += a1.x; a0.y += a1.y; a0.z += a1.z; a0.w += a1.w;

  if (w != 0) *reinterpret_cast<float4*>(&red[w - 1][c4]) = a0;
  __syncthreads();
  if (w == 0) {
#pragma unroll
    for (int r = 0; r < 3; ++r) {
      const float4 v = *reinterpret_cast<const float4*>(&red[r][c4]);
      a0.x += v.x; a0.y += v.y; a0.z += v.z; a0.w += v.w;
    }
    *reinterpret_cast<float4*>(&srow[c4]) = a0;
  }
  __syncthreads();

  // matvec: thread owns columns j and j+256 of H row g. srow[k] is an LDS
  // broadcast (conflict-free); Wfused rows are coalesced, L2-hot.
  const int j = threadIdx.x;
  float h0 = 0.f, h1 = 0.f;
#pragma unroll 8
  for (int k = 0; k < DDIM; ++k) {
    const float s = srow[k];
    const float* wk = Wfused + (size_t)k * HDIM + j;
    h0 += s * wk[0];
    h1 += s * wk[256];
  }
  const float cnt = (float)(end - start);
  h0 = fmaxf(h0 + cnt * bvec[j]       + b1[j],       0.f);
  h1 = fmaxf(h1 + cnt * bvec[j + 256] + b1[j + 256], 0.f);
  float* hp = H + (size_t)g * HDIM;
  hp[j]       = h0;
  hp[j + 256] = h1;
}

// ---------------------------------------------------------------------------
// out[M,256] = H[M,512] @ W2[512,256] + b2. BM=BN=64, BK=16, 256 thr, 4x4 acc.
// Next tile's global loads issued before the compute phase (latency hiding;
// grid is only 256 blocks = 1/CU, so ILP must cover the load latency).
// ---------------------------------------------------------------------------
__global__ __launch_bounds__(256) void gemm_out_kernel(
    int M, int N, int K, const float* __restrict__ A,
    const float* __restrict__ B, const float* __restrict__ bias,
    float* __restrict__ C) {
  __shared__ float As[16][64];  // As[k][m]
  __shared__ float Bs[16][64];  // Bs[k][n]
  const int m0 = blockIdx.y * 64, n0 = blockIdx.x * 64;
  const int tid = threadIdx.x;
  const int tx = tid & 15, ty = tid >> 4;
  const int ar = tid >> 2, ac = (tid & 3) << 2;   // A-load: row, col4
  const int br = tid >> 4, bc = (tid & 15) << 2;  // B-load: row, col4

  const float* Ap = A + (size_t)(m0 + ar) * K + ac;
  const float* Bp = B + (size_t)br * N + n0 + bc;

  float acc[4][4] = {};
  float4 av = *reinterpret_cast<const float4*>(Ap);
  float4 bv = *reinterpret_cast<const float4*>(Bp);

  for (int k0 = 0; k0 < K; k0 += 16) {
    __syncthreads();
    As[ac + 0][ar] = av.x;
    As[ac + 1][ar] = av.y;
    As[ac + 2][ar] = av.z;
    As[ac + 3][ar] = av.w;
    *reinterpret_cast<float4*>(&Bs[br][bc]) = bv;
    __syncthreads();
    if (k0 + 16 < K) {  // prefetch next tile while computing this one
      av = *reinterpret_cast<const float4*>(Ap + k0 + 16);
      bv = *reinterpret_cast<const float4*>(Bp + (size_t)(k0 + 16) * N);
    }
#pragma unroll
    for (int kk = 0; kk < 16; ++kk) {
      float a[4], b[4];
      *reinterpret_cast<float4*>(a) =
          *reinterpret_cast<const float4*>(&As[kk][ty << 2]);
      *reinterpret_cast<float4*>(b) =
          *reinterpret_cast<const float4*>(&Bs[kk][tx << 2]);
#pragma unroll
      for (int i2 = 0; i2 < 4; ++i2)
#pragma unroll
        for (int j2 = 0; j2 < 4; ++j2) acc[i2][j2] += a[i2] * b[j2];
    }
  }

  const float4 bias4 = *reinterpret_cast<const float4*>(bias + n0 + (tx << 2));
#pragma unroll
  for (int i2 = 0; i2 < 4; ++i2) {
    const int row = m0 + (ty << 2) + i2;
    float4 r;
    r.x = acc[i2][0] + bias4.x;
    r.y = acc[i2][1] + bias4.y;
    r.z = acc[i2][2] + bias4.z;
    r.w = acc[i2][3] + bias4.w;
    *reinterpret_cast<float4*>(C + (size_t)row * N + n0 + (tx << 2)) = r;
  }
}

extern "C" void kernel_launch(void* const* d_in, const int* in_sizes, int n_in,
                              void* d_out, int out_size, void* d_ws,
                              size_t ws_size, hipStream_t stream) {
  const float* x     = (const float*)d_in[0];
  const int*   batch = (const int*)d_in[1];
  const float* W_in  = (const float*)d_in[2];
  const float* b_in  = (const float*)d_in[3];
  const float* W1    = (const float*)d_in[4];
  const float* b1    = (const float*)d_in[5];
  const float* W2    = (const float*)d_in[6];
  const float* b2    = (const float*)d_in[7];
  float* out = (float*)d_out;

  const int N = in_sizes[1];       // 1,000,000 rows
  const int G = out_size / DDIM;   // 4096 segments

  // Workspace (floats): offsets[G+1] (as int) | Wfused[256*512] | bvec[512] | H[G*512]
  int*   offsets = (int*)d_ws;
  float* Wfused  = (float*)d_ws + (G + 2);
  float* bvec    = Wfused + (size_t)DDIM * HDIM;
  float* H       = bvec + HDIM;

  // 1) segment offsets via parallel binary search
  offsets_kernel<<<(G + 256) / 256, 256, 0, stream>>>(batch, offsets, N, G);

  // 2) Wfused = W_in @ W1, bvec = b_in @ W1 (one kernel, 514 blocks)
  wfused_kernel<<<2 * DDIM + 2, 256, 0, stream>>>(W_in, b_in, W1, Wfused, bvec);

  // 3) H = relu(segment_sum(x) @ Wfused + cnt*bvec + b1)   [G, 512]
  segsum_mlp_kernel<<<G, 256, 0, stream>>>(x, offsets, Wfused, bvec, b1, H);

  // 4) out = H @ W2 + b2                                    [G, 256]
  {
    dim3 grid(DDIM / 64, G / 64);
    gemm_out_kernel<<<grid, 256, 0, stream>>>(G, DDIM, HDIM, H, W2, b2, out);
  }
}

// Round 4
// 265.961 us; speedup vs baseline: 1.1873x; 1.1873x over previous
//
#include <hip/hip_runtime.h>

#define DDIM 256
#define HDIM 512

// ---------------------------------------------------------------------------
// offsets[t] = lower_bound(batch, t) for t in [0, G]; batch is sorted.
// ---------------------------------------------------------------------------
__global__ __launch_bounds__(256) void offsets_kernel(
    const int* __restrict__ batch, int* __restrict__ offsets, int N, int G) {
  const int t = blockIdx.x * 256 + threadIdx.x;
  if (t > G) return;
  int lo = 0, hi = N;
  while (lo < hi) {
    const int mid = (lo + hi) >> 1;
    if (batch[mid] < t) lo = mid + 1;
    else hi = mid;
  }
  offsets[t] = lo;
}

// ---------------------------------------------------------------------------
// Wfused[i,:] = W_in[i,:] @ W1  (blocks 0..511, two 256-col halves per row)
// bvec[:]     = b_in    @ W1    (blocks 512..513)
// ---------------------------------------------------------------------------
__global__ __launch_bounds__(256) void wfused_kernel(
    const float* __restrict__ W_in, const float* __restrict__ b_in,
    const float* __restrict__ W1, float* __restrict__ Wfused,
    float* __restrict__ bvec) {
  __shared__ float vrow[DDIM];
  const int b = blockIdx.x;
  const bool is_b = (b >= 2 * DDIM);
  const int i = is_b ? 0 : (b >> 1);
  const int half = is_b ? (b - 2 * DDIM) : (b & 1);
  const float* src = is_b ? b_in : (W_in + (size_t)i * DDIM);
  vrow[threadIdx.x] = src[threadIdx.x];
  __syncthreads();

  const int j = half * 256 + threadIdx.x;
  float h = 0.f;
#pragma unroll 8
  for (int k = 0; k < DDIM; ++k) h += vrow[k] * W1[(size_t)k * HDIM + j];
  if (is_b) bvec[j] = h;
  else Wfused[(size_t)i * HDIM + j] = h;
}

// ---------------------------------------------------------------------------
// Segment-sum, one block per segment. 4 waves; wave w owns rows start+w,
// +4, ... Four independent float4 accumulator streams per lane (16 rows in
// flight) to cover HBM latency. LDS cross-wave reduce, direct store.
// ---------------------------------------------------------------------------
__global__ __launch_bounds__(256) void segsum_kernel(
    const float* __restrict__ x, const int* __restrict__ offsets,
    float* __restrict__ S, float* __restrict__ counts) {
  const int g = blockIdx.x;
  const int start = offsets[g], end = offsets[g + 1];
  __shared__ float red[3][DDIM];

  const int w  = threadIdx.x >> 6;          // wave 0..3
  const int c4 = (threadIdx.x & 63) << 2;   // column base
  const float* xp = x + c4;

  float4 a0 = make_float4(0.f, 0.f, 0.f, 0.f);
  float4 a1 = make_float4(0.f, 0.f, 0.f, 0.f);
  float4 a2 = make_float4(0.f, 0.f, 0.f, 0.f);
  float4 a3 = make_float4(0.f, 0.f, 0.f, 0.f);

  int i = start + w;
  for (; i + 12 < end; i += 16) {
    const float4 v0 = *reinterpret_cast<const float4*>(xp + (size_t)i * DDIM);
    const float4 v1 = *reinterpret_cast<const float4*>(xp + (size_t)(i + 4) * DDIM);
    const float4 v2 = *reinterpret_cast<const float4*>(xp + (size_t)(i + 8) * DDIM);
    const float4 v3 = *reinterpret_cast<const float4*>(xp + (size_t)(i + 12) * DDIM);
    a0.x += v0.x; a0.y += v0.y; a0.z += v0.z; a0.w += v0.w;
    a1.x += v1.x; a1.y += v1.y; a1.z += v1.z; a1.w += v1.w;
    a2.x += v2.x; a2.y += v2.y; a2.z += v2.z; a2.w += v2.w;
    a3.x += v3.x; a3.y += v3.y; a3.z += v3.z; a3.w += v3.w;
  }
  for (; i < end; i += 4) {
    const float4 v0 = *reinterpret_cast<const float4*>(xp + (size_t)i * DDIM);
    a0.x += v0.x; a0.y += v0.y; a0.z += v0.z; a0.w += v0.w;
  }
  a0.x += a1.x; a0.y += a1.y; a0.z += a1.z; a0.w += a1.w;
  a2.x += a3.x; a2.y += a3.y; a2.z += a3.z; a2.w += a3.w;
  a0.x += a2.x; a0.y += a2.y; a0.z += a2.z; a0.w += a2.w;

  if (w != 0) *reinterpret_cast<float4*>(&red[w - 1][c4]) = a0;
  __syncthreads();
  if (w == 0) {
#pragma unroll
    for (int r = 0; r < 3; ++r) {
      const float4 v = *reinterpret_cast<const float4*>(&red[r][c4]);
      a0.x += v.x; a0.y += v.y; a0.z += v.z; a0.w += v.w;
    }
    *reinterpret_cast<float4*>(S + (size_t)g * DDIM + c4) = a0;
    if (threadIdx.x == 0) counts[g] = (float)(end - start);
  }
}

// ---------------------------------------------------------------------------
// fp32 tiled GEMM, BM=32, BN=64, BK=32, 256 threads, 2x4 acc/thread.
// Next-tile global prefetch issued before the compute phase. A-tile stored
// transposed in LDS.  BIAS_MODE: 1 = +bias[j]; 2 = +counts[row]*bvec[j]+bias[j]
// ---------------------------------------------------------------------------
template <bool RELU, int BIAS_MODE>
__global__ __launch_bounds__(256) void gemm32x64_kernel(
    int M, int N, int K, const float* __restrict__ A,
    const float* __restrict__ B, const float* __restrict__ bias,
    const float* __restrict__ bvec, const float* __restrict__ counts,
    float* __restrict__ C) {
  __shared__ float As[32][32];  // As[k][m]
  __shared__ float Bs[32][64];  // Bs[k][n]
  const int m0 = blockIdx.y * 32, n0 = blockIdx.x * 64;
  const int tid = threadIdx.x;
  const int tx = tid & 15, ty = tid >> 4;          // output: col group, row group
  const int ar = tid >> 3, ac = (tid & 7) << 2;    // A-load: row 0..31, col4
  const int br = tid >> 4, bc = (tid & 15) << 2;   // B-load: rows br, br+16

  const float* Ap = A + (size_t)(m0 + ar) * K + ac;
  const float* B0 = B + (size_t)br * N + n0 + bc;
  const float* B1 = B + (size_t)(br + 16) * N + n0 + bc;

  float acc[2][4] = {};
  float4 av  = *reinterpret_cast<const float4*>(Ap);
  float4 bv0 = *reinterpret_cast<const float4*>(B0);
  float4 bv1 = *reinterpret_cast<const float4*>(B1);

  for (int k0 = 0; k0 < K; k0 += 32) {
    __syncthreads();
    As[ac + 0][ar] = av.x;
    As[ac + 1][ar] = av.y;
    As[ac + 2][ar] = av.z;
    As[ac + 3][ar] = av.w;
    *reinterpret_cast<float4*>(&Bs[br][bc])      = bv0;
    *reinterpret_cast<float4*>(&Bs[br + 16][bc]) = bv1;
    __syncthreads();
    if (k0 + 32 < K) {  // prefetch next k-tile during compute
      av  = *reinterpret_cast<const float4*>(Ap + k0 + 32);
      bv0 = *reinterpret_cast<const float4*>(B0 + (size_t)(k0 + 32) * N);
      bv1 = *reinterpret_cast<const float4*>(B1 + (size_t)(k0 + 32) * N);
    }
#pragma unroll
    for (int kk = 0; kk < 32; ++kk) {
      float a[2], b[4];
      *reinterpret_cast<float2*>(a) =
          *reinterpret_cast<const float2*>(&As[kk][ty << 1]);
      *reinterpret_cast<float4*>(b) =
          *reinterpret_cast<const float4*>(&Bs[kk][tx << 2]);
#pragma unroll
      for (int i2 = 0; i2 < 2; ++i2)
#pragma unroll
        for (int j2 = 0; j2 < 4; ++j2) acc[i2][j2] += a[i2] * b[j2];
    }
  }

  float4 bias4 = *reinterpret_cast<const float4*>(bias + n0 + (tx << 2));
  float4 bvec4 = make_float4(0.f, 0.f, 0.f, 0.f);
  if (BIAS_MODE == 2)
    bvec4 = *reinterpret_cast<const float4*>(bvec + n0 + (tx << 2));

#pragma unroll
  for (int i2 = 0; i2 < 2; ++i2) {
    const int row = m0 + (ty << 1) + i2;
    float cnt = 0.f;
    if (BIAS_MODE == 2) cnt = counts[row];
    float4 r;
    r.x = acc[i2][0] + bias4.x + cnt * bvec4.x;
    r.y = acc[i2][1] + bias4.y + cnt * bvec4.y;
    r.z = acc[i2][2] + bias4.z + cnt * bvec4.z;
    r.w = acc[i2][3] + bias4.w + cnt * bvec4.w;
    if (RELU) {
      r.x = fmaxf(r.x, 0.f);
      r.y = fmaxf(r.y, 0.f);
      r.z = fmaxf(r.z, 0.f);
      r.w = fmaxf(r.w, 0.f);
    }
    *reinterpret_cast<float4*>(C + (size_t)row * N + n0 + (tx << 2)) = r;
  }
}

extern "C" void kernel_launch(void* const* d_in, const int* in_sizes, int n_in,
                              void* d_out, int out_size, void* d_ws,
                              size_t ws_size, hipStream_t stream) {
  const float* x     = (const float*)d_in[0];
  const int*   batch = (const int*)d_in[1];
  const float* W_in  = (const float*)d_in[2];
  const float* b_in  = (const float*)d_in[3];
  const float* W1    = (const float*)d_in[4];
  const float* b1    = (const float*)d_in[5];
  const float* W2    = (const float*)d_in[6];
  const float* b2    = (const float*)d_in[7];
  float* out = (float*)d_out;

  const int N = in_sizes[1];       // 1,000,000 rows
  const int G = out_size / DDIM;   // 4096 segments

  // Workspace (floats): offsets[G+1] (int) | Wfused[256*512] | bvec[512]
  //                     | S[G*256] | counts[G] | H[G*512]
  int*   offsets = (int*)d_ws;
  float* Wfused  = (float*)d_ws + (G + 2);
  float* bvec    = Wfused + (size_t)DDIM * HDIM;
  float* S       = bvec + HDIM;
  float* counts  = S + (size_t)G * DDIM;
  float* H       = counts + G;

  // 1) segment offsets via parallel binary search
  offsets_kernel<<<(G + 256) / 256, 256, 0, stream>>>(batch, offsets, N, G);

  // 2) Wfused = W_in @ W1, bvec = b_in @ W1
  wfused_kernel<<<2 * DDIM + 2, 256, 0, stream>>>(W_in, b_in, W1, Wfused, bvec);

  // 3) S = segment_sum(x), counts[g] = |segment g|
  segsum_kernel<<<G, 256, 0, stream>>>(x, offsets, S, counts);

  // 4) H = relu(S @ Wfused + counts ⊗ bvec + b1)   [G, 512]
  {
    dim3 grid(HDIM / 64, G / 32);   // 8 x 128 = 1024 blocks
    gemm32x64_kernel<true, 2><<<grid, 256, 0, stream>>>(
        G, HDIM, DDIM, S, Wfused, b1, bvec, counts, H);
  }
  // 5) out = H @ W2 + b2                           [G, 256]
  {
    dim3 grid(DDIM / 64, G / 32);   // 4 x 128 = 512 blocks
    gemm32x64_kernel<false, 1><<<grid, 256, 0, stream>>>(
        G, DDIM, HDIM, H, W2, b2, nullptr, nullptr, out);
  }
}

// Round 6
// 226.385 us; speedup vs baseline: 1.3949x; 1.1748x over previous
//
#include <hip/hip_runtime.h>

#define DDIM 256
#define HDIM 512

typedef float f32x4 __attribute__((ext_vector_type(4)));

// ---------------------------------------------------------------------------
// offsets[t] = lower_bound(batch, t) for t in [0, G]; batch is sorted.
// ---------------------------------------------------------------------------
__global__ __launch_bounds__(256) void offsets_kernel(
    const int* __restrict__ batch, int* __restrict__ offsets, int N, int G) {
  const int t = blockIdx.x * 256 + threadIdx.x;
  if (t > G) return;
  int lo = 0, hi = N;
  while (lo < hi) {
    const int mid = (lo + hi) >> 1;
    if (batch[mid] < t) lo = mid + 1;
    else hi = mid;
  }
  offsets[t] = lo;
}

// ---------------------------------------------------------------------------
// Wfused[i,:] = W_in[i,:] @ W1  (blocks 0..511, two 256-col halves per row)
// bvec[:]     = b_in    @ W1    (blocks 512..513)
// ---------------------------------------------------------------------------
__global__ __launch_bounds__(256) void wfused_kernel(
    const float* __restrict__ W_in, const float* __restrict__ b_in,
    const float* __restrict__ W1, float* __restrict__ Wfused,
    float* __restrict__ bvec) {
  __shared__ float vrow[DDIM];
  const int b = blockIdx.x;
  const bool is_b = (b >= 2 * DDIM);
  const int i = is_b ? 0 : (b >> 1);
  const int half = is_b ? (b - 2 * DDIM) : (b & 1);
  const float* src = is_b ? b_in : (W_in + (size_t)i * DDIM);
  vrow[threadIdx.x] = src[threadIdx.x];
  __syncthreads();

  const int j = half * 256 + threadIdx.x;
  float h = 0.f;
#pragma unroll 8
  for (int k = 0; k < DDIM; ++k) h += vrow[k] * W1[(size_t)k * HDIM + j];
  if (is_b) bvec[j] = h;
  else Wfused[(size_t)i * HDIM + j] = h;
}

// ---------------------------------------------------------------------------
// Segment-sum, one block per segment. 4 waves; wave w owns rows ≡ w (mod 4),
// 4 independent float4 accumulator streams (16 rows in flight). Nontemporal
// loads: x is 1 GB pure streaming, keep it out of L2. LDS cross-wave reduce.
// ---------------------------------------------------------------------------
__global__ __launch_bounds__(256) void segsum_kernel(
    const float* __restrict__ x, const int* __restrict__ offsets,
    float* __restrict__ S, float* __restrict__ counts) {
  const int g = blockIdx.x;
  const int start = offsets[g], end = offsets[g + 1];
  __shared__ float red[3][DDIM];

  const int w  = threadIdx.x >> 6;          // wave 0..3
  const int c4 = (threadIdx.x & 63) << 2;   // column base
  const float* xp = x + c4;

  f32x4 a0 = {0.f, 0.f, 0.f, 0.f};
  f32x4 a1 = {0.f, 0.f, 0.f, 0.f};
  f32x4 a2 = {0.f, 0.f, 0.f, 0.f};
  f32x4 a3 = {0.f, 0.f, 0.f, 0.f};

  int i = start + w;
  for (; i + 12 < end; i += 16) {
    const f32x4 v0 = __builtin_nontemporal_load(
        reinterpret_cast<const f32x4*>(xp + (size_t)i * DDIM));
    const f32x4 v1 = __builtin_nontemporal_load(
        reinterpret_cast<const f32x4*>(xp + (size_t)(i + 4) * DDIM));
    const f32x4 v2 = __builtin_nontemporal_load(
        reinterpret_cast<const f32x4*>(xp + (size_t)(i + 8) * DDIM));
    const f32x4 v3 = __builtin_nontemporal_load(
        reinterpret_cast<const f32x4*>(xp + (size_t)(i + 12) * DDIM));
    a0 += v0;
    a1 += v1;
    a2 += v2;
    a3 += v3;
  }
  for (; i < end; i += 4) {
    const f32x4 v0 = __builtin_nontemporal_load(
        reinterpret_cast<const f32x4*>(xp + (size_t)i * DDIM));
    a0 += v0;
  }
  a0 += a1;
  a2 += a3;
  a0 += a2;

  if (w != 0) *reinterpret_cast<f32x4*>(&red[w - 1][c4]) = a0;
  __syncthreads();
  if (w == 0) {
#pragma unroll
    for (int r = 0; r < 3; ++r) {
      a0 += *reinterpret_cast<const f32x4*>(&red[r][c4]);
    }
    *reinterpret_cast<f32x4*>(S + (size_t)g * DDIM + c4) = a0;
    if (threadIdx.x == 0) counts[g] = (float)(end - start);
  }
}

// ---------------------------------------------------------------------------
// fp32 tiled GEMM, BM=BN=64, BK=32, 256 threads, 4x4 acc (2 B LDS / FMA).
// A-tile transposed in LDS; rows padded to 68 floats (bank de-alias, keeps
// 16B alignment). Next-tile global prefetch before compute phase.
// BIAS_MODE: 0 none; 1 +bias[j]; 2 +counts[row]*bvec[j]+bias[j]
// ---------------------------------------------------------------------------
template <bool RELU, int BIAS_MODE>
__global__ __launch_bounds__(256) void gemm64x64_kernel(
    int M, int N, int K, const float* __restrict__ A,
    const float* __restrict__ B, const float* __restrict__ bias,
    const float* __restrict__ bvec, const float* __restrict__ counts,
    float* __restrict__ C) {
  __shared__ float As[32][68];  // As[k][m], padded
  __shared__ float Bs[32][68];  // Bs[k][n], padded
  const int m0 = blockIdx.y * 64, n0 = blockIdx.x * 64;
  const int tid = threadIdx.x;
  const int tx = tid & 15, ty = tid >> 4;         // output 4x4 block coords
  const int ar = tid >> 2, ac = (tid & 3) << 3;   // A-load: row 0..63, col8
  const int br = tid >> 3, bc = (tid & 7) << 3;   // B-load: row 0..31, col8

  const float* Ap = A + (size_t)(m0 + ar) * K + ac;
  const float* Bp = B + (size_t)br * N + n0 + bc;

  float acc[4][4] = {};
  float4 av0 = *reinterpret_cast<const float4*>(Ap);
  float4 av1 = *reinterpret_cast<const float4*>(Ap + 4);
  float4 bv0 = *reinterpret_cast<const float4*>(Bp);
  float4 bv1 = *reinterpret_cast<const float4*>(Bp + 4);

  for (int k0 = 0; k0 < K; k0 += 32) {
    __syncthreads();
    As[ac + 0][ar] = av0.x;
    As[ac + 1][ar] = av0.y;
    As[ac + 2][ar] = av0.z;
    As[ac + 3][ar] = av0.w;
    As[ac + 4][ar] = av1.x;
    As[ac + 5][ar] = av1.y;
    As[ac + 6][ar] = av1.z;
    As[ac + 7][ar] = av1.w;
    *reinterpret_cast<float4*>(&Bs[br][bc])     = bv0;
    *reinterpret_cast<float4*>(&Bs[br][bc + 4]) = bv1;
    __syncthreads();
    if (k0 + 32 < K) {  // prefetch next k-tile during compute
      av0 = *reinterpret_cast<const float4*>(Ap + k0 + 32);
      av1 = *reinterpret_cast<const float4*>(Ap + k0 + 36);
      bv0 = *reinterpret_cast<const float4*>(Bp + (size_t)(k0 + 32) * N);
      bv1 = *reinterpret_cast<const float4*>(Bp + (size_t)(k0 + 32) * N + 4);
    }
#pragma unroll
    for (int kk = 0; kk < 32; ++kk) {
      float a[4], b[4];
      *reinterpret_cast<float4*>(a) =
          *reinterpret_cast<const float4*>(&As[kk][ty << 2]);
      *reinterpret_cast<float4*>(b) =
          *reinterpret_cast<const float4*>(&Bs[kk][tx << 2]);
#pragma unroll
      for (int i2 = 0; i2 < 4; ++i2)
#pragma unroll
        for (int j2 = 0; j2 < 4; ++j2) acc[i2][j2] += a[i2] * b[j2];
    }
  }

  float4 bias4 = make_float4(0.f, 0.f, 0.f, 0.f);
  float4 bvec4 = make_float4(0.f, 0.f, 0.f, 0.f);
  if (BIAS_MODE >= 1)
    bias4 = *reinterpret_cast<const float4*>(bias + n0 + (tx << 2));
  if (BIAS_MODE == 2)
    bvec4 = *reinterpret_cast<const float4*>(bvec + n0 + (tx << 2));

#pragma unroll
  for (int i2 = 0; i2 < 4; ++i2) {
    const int row = m0 + (ty << 2) + i2;
    float cnt = 0.f;
    if (BIAS_MODE == 2) cnt = counts[row];
    float4 r;
    r.x = acc[i2][0] + bias4.x + cnt * bvec4.x;
    r.y = acc[i2][1] + bias4.y + cnt * bvec4.y;
    r.z = acc[i2][2] + bias4.z + cnt * bvec4.z;
    r.w = acc[i2][3] + bias4.w + cnt * bvec4.w;
    if (RELU) {
      r.x = fmaxf(r.x, 0.f);
      r.y = fmaxf(r.y, 0.f);
      r.z = fmaxf(r.z, 0.f);
      r.w = fmaxf(r.w, 0.f);
    }
    *reinterpret_cast<float4*>(C + (size_t)row * N + n0 + (tx << 2)) = r;
  }
}

extern "C" void kernel_launch(void* const* d_in, const int* in_sizes, int n_in,
                              void* d_out, int out_size, void* d_ws,
                              size_t ws_size, hipStream_t stream) {
  const float* x     = (const float*)d_in[0];
  const int*   batch = (const int*)d_in[1];
  const float* W_in  = (const float*)d_in[2];
  const float* b_in  = (const float*)d_in[3];
  const float* W1    = (const float*)d_in[4];
  const float* b1    = (const float*)d_in[5];
  const float* W2    = (const float*)d_in[6];
  const float* b2    = (const float*)d_in[7];
  float* out = (float*)d_out;

  const int N = in_sizes[1];       // 1,000,000 rows
  const int G = out_size / DDIM;   // 4096 segments

  // Workspace (floats): offsets[G+1] (int) | Wfused[256*512] | bvec[512]
  //                     | S[G*256] | counts[G] | H[G*512]
  int*   offsets = (int*)d_ws;
  float* Wfused  = (float*)d_ws + (G + 2);
  float* bvec    = Wfused + (size_t)DDIM * HDIM;
  float* S       = bvec + HDIM;
  float* counts  = S + (size_t)G * DDIM;
  float* H       = counts + G;

  // 1) segment offsets via parallel binary search
  offsets_kernel<<<(G + 256) / 256, 256, 0, stream>>>(batch, offsets, N, G);

  // 2) Wfused = W_in @ W1, bvec = b_in @ W1
  wfused_kernel<<<2 * DDIM + 2, 256, 0, stream>>>(W_in, b_in, W1, Wfused, bvec);

  // 3) S = segment_sum(x), counts[g] = |segment g|
  segsum_kernel<<<G, 256, 0, stream>>>(x, offsets, S, counts);

  // 4) H = relu(S @ Wfused + counts ⊗ bvec + b1)   [G, 512]
  {
    dim3 grid(HDIM / 64, G / 64);   // 8 x 64 = 512 blocks
    gemm64x64_kernel<true, 2><<<grid, 256, 0, stream>>>(
        G, HDIM, DDIM, S, Wfused, b1, bvec, counts, H);
  }
  // 5) out = H @ W2 + b2                           [G, 256]
  {
    dim3 grid(DDIM / 64, G / 64);   // 4 x 64 = 256 blocks
    gemm64x64_kernel<false, 1><<<grid, 256, 0, stream>>>(
        G, DDIM, HDIM, H, W2, b2, nullptr, nullptr, out);
  }
}